// Round 7
// baseline (574.249 us; speedup 1.0000x reference)
//
#include <hip/hip_runtime.h>
#include <stdint.h>

#define DMODEL 1024
#define NHEADS 16
#define HDIM   64
#define BB     4
#define SS     2048
#define MM     (BB*SS)                      // 8192 rows
#define QKV_ELEMS ((size_t)8388608)         // B*S*DMODEL

typedef unsigned short ushort_t;
typedef __bf16    bf16x8  __attribute__((ext_vector_type(8)));
typedef _Float16  half4   __attribute__((ext_vector_type(4)));
typedef _Float16  half2_t __attribute__((ext_vector_type(2)));
typedef float     floatx4 __attribute__((ext_vector_type(4)));

__device__ inline ushort_t f32_to_bf16(float f) {
    union { float f; uint32_t u; } v; v.f = f;
    uint32_t r = v.u + 0x7FFF + ((v.u >> 16) & 1);   // RNE
    return (ushort_t)(r >> 16);
}
__device__ inline ushort_t f32_to_f16u(float f) {
    union { _Float16 h; ushort_t u; } v; v.h = (_Float16)f; return v.u;
}
__device__ inline half2_t pkrtz(float a, float b) {
    return __builtin_bit_cast(half2_t, __builtin_amdgcn_cvt_pkrtz(a, b));
}
__device__ inline void glds16(const void* g, void* l) {
    __builtin_amdgcn_global_load_lds(
        (const __attribute__((address_space(1))) unsigned int*)g,
        (__attribute__((address_space(3))) unsigned int*)l, 16, 0, 0);
}

// ---------------------------------------------------------------------------
// fp32 -> bf16 elementwise convert; each block converts 2048 elements.
// ---------------------------------------------------------------------------
__global__ __launch_bounds__(256) void convert_bf16(const float* __restrict__ in,
                                                    ushort_t* __restrict__ out) {
    size_t i = ((size_t)blockIdx.x * 256 + threadIdx.x) * 8;
    float4 a = *(const float4*)&in[i];
    float4 b = *(const float4*)&in[i + 4];
    ushort_t t[8];
    t[0] = f32_to_bf16(a.x); t[1] = f32_to_bf16(a.y);
    t[2] = f32_to_bf16(a.z); t[3] = f32_to_bf16(a.w);
    t[4] = f32_to_bf16(b.x); t[5] = f32_to_bf16(b.y);
    t[6] = f32_to_bf16(b.z); t[7] = f32_to_bf16(b.w);
    *(uint4*)&out[i] = *(uint4*)t;
}

__global__ __launch_bounds__(256) void convert_w3(
    const float* __restrict__ w0, const float* __restrict__ w1, const float* __restrict__ w2,
    ushort_t* __restrict__ o0, ushort_t* __restrict__ o1, ushort_t* __restrict__ o2) {
    const float* src = (blockIdx.y == 0) ? w0 : (blockIdx.y == 1) ? w1 : w2;
    ushort_t*    dst = (blockIdx.y == 0) ? o0 : (blockIdx.y == 1) ? o1 : o2;
    size_t i = ((size_t)blockIdx.x * 256 + threadIdx.x) * 8;
    float4 a = *(const float4*)&src[i];
    float4 b = *(const float4*)&src[i + 4];
    ushort_t t[8];
    t[0] = f32_to_bf16(a.x); t[1] = f32_to_bf16(a.y);
    t[2] = f32_to_bf16(a.z); t[3] = f32_to_bf16(a.w);
    t[4] = f32_to_bf16(b.x); t[5] = f32_to_bf16(b.y);
    t[6] = f32_to_bf16(b.z); t[7] = f32_to_bf16(b.w);
    *(uint4*)&dst[i] = *(uint4*)t;
}

// ---------------------------------------------------------------------------
// bf16 GEMM (v5 structure): 3-buffer LDS, counted vmcnt(4) pipeline,
// m-panel->XCD affinity, T2 swizzle (linear glds dest + swizzled src/read).
// OUT: 0 = bf16 scatter to [B,H,S,HDIM]; 1 = f16 scatter; 2 = fp32 [M,DMODEL]
// ---------------------------------------------------------------------------
template<int OUT>
__global__ __launch_bounds__(256) void gemm_bf16(
    const ushort_t* __restrict__ A, const ushort_t* __restrict__ W,
    const float* __restrict__ bias, void* __restrict__ O, float scale)
{
    __shared__ ushort_t As[3 * 4096];   // 3 bufs x 8 KiB
    __shared__ ushort_t Bs[3 * 4096];

    const int tid  = threadIdx.x;
    const int lane = tid & 63;
    const int quad = lane >> 4;
    const int l15  = lane & 15;
    const int wid  = tid >> 6;
    const int wr   = wid >> 1, wc = wid & 1;

    const int bid = blockIdx.x;
    const int n0  = ((bid >> 3) & 7) * 128;
    const int m0  = ((bid & 7) + ((bid >> 6) << 3)) * 128;

    floatx4 acc[4][4];
    #pragma unroll
    for (int i = 0; i < 4; i++)
        #pragma unroll
        for (int j = 0; j < 4; j++)
            acc[i][j] = (floatx4){0.f, 0.f, 0.f, 0.f};

    auto stage = [&](int kk, int bufB) {
        #pragma unroll
        for (int j = 0; j < 2; j++) {
            const int p  = tid + j * 256;
            const int ph = p << 4;
            const int lg = ph ^ (((ph >> 7) & 7) << 4);
            const int row = lg >> 6, cc = (lg >> 4) & 3;
            glds16(&A[(size_t)(m0 + row) * DMODEL + kk + cc * 8], (char*)As + bufB + ph);
            glds16(&W[(size_t)(n0 + row) * DMODEL + kk + cc * 8], (char*)Bs + bufB + ph);
        }
    };

    stage(0, 0);
    stage(32, 8192);

    int cbB = 0;
    for (int k0 = 0; k0 < DMODEL; k0 += 32) {
        if (k0 + 32 < DMODEL) asm volatile("s_waitcnt vmcnt(4)" ::: "memory");
        else                  asm volatile("s_waitcnt vmcnt(0)" ::: "memory");
        __builtin_amdgcn_s_barrier();
        __builtin_amdgcn_sched_barrier(0);
        const int k2 = k0 + 64;
        if (k2 < DMODEL) {
            int nbB = cbB + 16384; if (nbB >= 24576) nbB -= 24576;
            stage(k2, nbB);
        }
        bf16x8 af[4], bfv[4];
        #pragma unroll
        for (int i = 0; i < 4; i++) {
            const int r = wr * 64 + i * 16 + l15;
            const int L = (r << 6) | (quad << 4);
            af[i] = *(const bf16x8*)((const char*)As + cbB + (L ^ (((r >> 1) & 7) << 4)));
        }
        #pragma unroll
        for (int j = 0; j < 4; j++) {
            const int r = wc * 64 + j * 16 + l15;
            const int L = (r << 6) | (quad << 4);
            bfv[j] = *(const bf16x8*)((const char*)Bs + cbB + (L ^ (((r >> 1) & 7) << 4)));
        }
        #pragma unroll
        for (int i = 0; i < 4; i++)
            #pragma unroll
            for (int j = 0; j < 4; j++)
                acc[i][j] = __builtin_amdgcn_mfma_f32_16x16x32_bf16(af[i], bfv[j], acc[i][j], 0, 0, 0);
        cbB += 8192; if (cbB == 24576) cbB = 0;
    }

    #pragma unroll
    for (int j = 0; j < 4; j++) {
        const int n = n0 + wc * 64 + j * 16 + l15;
        const float bn = bias[n];
        #pragma unroll
        for (int i = 0; i < 4; i++) {
            #pragma unroll
            for (int r = 0; r < 4; r++) {
                const int m = m0 + wr * 64 + i * 16 + quad * 4 + r;
                float v = (acc[i][j][r] + bn) * scale;
                if (OUT == 0) {
                    const int b = m >> 11, s = m & 2047;
                    const int hh = n >> 6, dh = n & 63;
                    ((ushort_t*)O)[(((size_t)(b * NHEADS + hh)) * SS + s) * HDIM + dh] = f32_to_bf16(v);
                } else if (OUT == 1) {
                    const int b = m >> 11, s = m & 2047;
                    const int hh = n >> 6, dh = n & 63;
                    ((ushort_t*)O)[(((size_t)(b * NHEADS + hh)) * SS + s) * HDIM + dh] = f32_to_f16u(v);
                } else {
                    ((float*)O)[(size_t)m * DMODEL + n] = v;
                }
            }
        }
    }
}

// ---------------------------------------------------------------------------
// Batched Q+K projection GEMM: grid 1024 = 2 GEMMs x 512 blocks; g = bid>>9
// selects A/W/bias/out/scale. Inner loop identical to gemm_bf16 (glds16 path
// -- round-6 showed reg-staged A breaks the pipeline; this keeps it). 3
// blocks/CU resident during this span (48 KiB LDS); one dispatch tail saved.
// ---------------------------------------------------------------------------
__global__ __launch_bounds__(256) void gemm_qk(
    const ushort_t* __restrict__ A0, const ushort_t* __restrict__ A1,
    const ushort_t* __restrict__ W0, const ushort_t* __restrict__ W1,
    const float* __restrict__ b0, const float* __restrict__ b1,
    ushort_t* __restrict__ O0, ushort_t* __restrict__ O1, float scale0)
{
    __shared__ ushort_t As[3 * 4096];
    __shared__ ushort_t Bs[3 * 4096];

    const int tid  = threadIdx.x;
    const int lane = tid & 63;
    const int quad = lane >> 4;
    const int l15  = lane & 15;
    const int wid  = tid >> 6;
    const int wr   = wid >> 1, wc = wid & 1;

    const int bid = blockIdx.x;
    const int g   = bid >> 9;
    const int b9  = bid & 511;
    const int n0  = ((b9 >> 3) & 7) * 128;
    const int m0  = ((b9 & 7) + ((b9 >> 6) << 3)) * 128;

    const ushort_t* A    = g ? A1 : A0;
    const ushort_t* W    = g ? W1 : W0;
    const float*    bias = g ? b1 : b0;
    ushort_t*       Oz   = g ? O1 : O0;
    const float     scale = g ? 1.0f : scale0;

    floatx4 acc[4][4];
    #pragma unroll
    for (int i = 0; i < 4; i++)
        #pragma unroll
        for (int j = 0; j < 4; j++)
            acc[i][j] = (floatx4){0.f, 0.f, 0.f, 0.f};

    auto stage = [&](int kk, int bufB) {
        #pragma unroll
        for (int j = 0; j < 2; j++) {
            const int p  = tid + j * 256;
            const int ph = p << 4;
            const int lg = ph ^ (((ph >> 7) & 7) << 4);
            const int row = lg >> 6, cc = (lg >> 4) & 3;
            glds16(&A[(size_t)(m0 + row) * DMODEL + kk + cc * 8], (char*)As + bufB + ph);
            glds16(&W[(size_t)(n0 + row) * DMODEL + kk + cc * 8], (char*)Bs + bufB + ph);
        }
    };

    stage(0, 0);
    stage(32, 8192);

    int cbB = 0;
    for (int k0 = 0; k0 < DMODEL; k0 += 32) {
        if (k0 + 32 < DMODEL) asm volatile("s_waitcnt vmcnt(4)" ::: "memory");
        else                  asm volatile("s_waitcnt vmcnt(0)" ::: "memory");
        __builtin_amdgcn_s_barrier();
        __builtin_amdgcn_sched_barrier(0);
        const int k2 = k0 + 64;
        if (k2 < DMODEL) {
            int nbB = cbB + 16384; if (nbB >= 24576) nbB -= 24576;
            stage(k2, nbB);
        }
        bf16x8 af[4], bfv[4];
        #pragma unroll
        for (int i = 0; i < 4; i++) {
            const int r = wr * 64 + i * 16 + l15;
            const int L = (r << 6) | (quad << 4);
            af[i] = *(const bf16x8*)((const char*)As + cbB + (L ^ (((r >> 1) & 7) << 4)));
        }
        #pragma unroll
        for (int j = 0; j < 4; j++) {
            const int r = wc * 64 + j * 16 + l15;
            const int L = (r << 6) | (quad << 4);
            bfv[j] = *(const bf16x8*)((const char*)Bs + cbB + (L ^ (((r >> 1) & 7) << 4)));
        }
        #pragma unroll
        for (int i = 0; i < 4; i++)
            #pragma unroll
            for (int j = 0; j < 4; j++)
                acc[i][j] = __builtin_amdgcn_mfma_f32_16x16x32_bf16(af[i], bfv[j], acc[i][j], 0, 0, 0);
        cbB += 8192; if (cbB == 24576) cbB = 0;
    }

    #pragma unroll
    for (int j = 0; j < 4; j++) {
        const int n = n0 + wc * 64 + j * 16 + l15;
        const float bn = bias[n];
        #pragma unroll
        for (int i = 0; i < 4; i++) {
            #pragma unroll
            for (int r = 0; r < 4; r++) {
                const int m = m0 + wr * 64 + i * 16 + quad * 4 + r;
                const float v = (acc[i][j][r] + bn) * scale;
                const int bb = m >> 11, s = m & 2047;
                const int hh = n >> 6, dh = n & 63;
                Oz[(((size_t)(bb * NHEADS + hh)) * SS + s) * HDIM + dh] = f32_to_bf16(v);
            }
        }
    }
}

// ---------------------------------------------------------------------------
// Flash attention v3 (round-5 form, known 98.8 us, VGPR=64) + T5 setprio
// around the MFMA clusters. Static-max softmax (log2-domain scores,
// p = exp2(s), running max deleted); PV via 16x16x16 f16.
// ---------------------------------------------------------------------------
__global__ __launch_bounds__(256, 4) void attn_kernel(
    const ushort_t* __restrict__ Q, const ushort_t* __restrict__ K,
    const ushort_t* __restrict__ V, ushort_t* __restrict__ ctx)
{
    constexpr int LDV = 72;
    constexpr int VOFF = 2 * 4096;                       // Vt region base
    __shared__ ushort_t smem[2 * 4096 + 2 * 64 * LDV];   // 34.0 KiB
    ushort_t* Tr = smem;                                 // epilogue scratch

    const int tid  = threadIdx.x;
    const int lane = tid & 63;
    const int wid  = tid >> 6;
    const int quad = lane >> 4;
    const int l15  = lane & 15;
    const int bid  = blockIdx.x;
    const int bh   = (bid & 7) * 8 + (bid >> 7);          // same head -> same XCD
    const int b    = bh >> 4, h = bh & 15;
    const int q0   = ((bid >> 3) & 15) * 128 + wid * 32;

    const ushort_t* Qb = Q + (size_t)bh * SS * HDIM;
    const ushort_t* Kb = K + (size_t)bh * SS * HDIM;
    const ushort_t* Vb = V + (size_t)bh * SS * HDIM;

    // Q fragments (B-operand: lane&15 = q, quad*8+j = dim), 2 q-tiles
    bf16x8 qf[2][2];
    #pragma unroll
    for (int qt = 0; qt < 2; qt++)
        #pragma unroll
        for (int c = 0; c < 2; c++)
            qf[qt][c] = *(const bf16x8*)&Qb[(size_t)(q0 + qt * 16 + l15) * HDIM + c * 32 + quad * 8];

    floatx4 acc[2][4];
    #pragma unroll
    for (int qt = 0; qt < 2; qt++)
        #pragma unroll
        for (int dt = 0; dt < 4; dt++)
            acc[qt][dt] = (floatx4){0.f, 0.f, 0.f, 0.f};
    float lrun[2] = {0.f, 0.f};     // per-lane partial sum of p (reduced at end)

    const int kp = tid & 31;    // key pair for V staging
    const int dc = tid >> 5;    // dim chunk for V staging

    // ---- prologue: stage tile 0 ----
    #pragma unroll
    for (int j = 0; j < 2; j++) {
        const int p = tid + j * 256, row = p >> 3, cc = (p & 7) ^ (row & 7);
        glds16(&Kb[(size_t)row * HDIM + cc * 8], &smem[p * 8]);
    }
    {
        ushort_t ua[8], ub[8];
        *(uint4*)ua = *(const uint4*)&Vb[(size_t)(2 * kp) * HDIM + dc * 8];
        *(uint4*)ub = *(const uint4*)&Vb[(size_t)(2 * kp + 1) * HDIM + dc * 8];
        #pragma unroll
        for (int i = 0; i < 8; i++)
            *(uint32_t*)&smem[VOFF + (dc * 8 + i) * LDV + 2 * kp] = (uint32_t)ua[i] | ((uint32_t)ub[i] << 16);
    }

    const half2_t one2 = {(_Float16)1.f, (_Float16)1.f};

    for (int kt = 0; kt < SS; kt += 64) {
        const int cur = ((kt >> 6) & 1);
        const int ko  = cur * 4096;                  // current K buf offset
        const int kon = 4096 - ko;                   // next K buf offset
        const int vo  = VOFF + cur * (64 * LDV);     // current Vt buf offset
        const int von = VOFF + (64 * LDV) - cur * (64 * LDV);
        __syncthreads();   // tile(kt) staged; other buffers free

        // ---- prefetch tile kt+64 (wraps on last iter; harmless) ----
        const int ktn = (kt + 64) & (SS - 1);
        #pragma unroll
        for (int j = 0; j < 2; j++) {
            const int p = tid + j * 256, row = p >> 3, cc = (p & 7) ^ (row & 7);
            glds16(&Kb[(size_t)(ktn + row) * HDIM + cc * 8], &smem[kon + p * 8]);
        }
        ushort_t ua[8], ub[8];
        *(uint4*)ua = *(const uint4*)&Vb[(size_t)(ktn + 2 * kp) * HDIM + dc * 8];
        *(uint4*)ub = *(const uint4*)&Vb[(size_t)(ktn + 2 * kp + 1) * HDIM + dc * 8];

        // ---- fragments for tile kt ----
        bf16x8 kf[4][2];
        #pragma unroll
        for (int nt = 0; nt < 4; nt++) {
            const int row = nt * 16 + l15;
            #pragma unroll
            for (int c = 0; c < 2; c++) {
                const int pos = (c * 4 + quad) ^ (row & 7);
                kf[nt][c] = *(const bf16x8*)&smem[ko + row * 64 + pos * 8];
            }
        }
        half4 vf[4][4];
        #pragma unroll
        for (int kb = 0; kb < 4; kb++)
            #pragma unroll
            for (int dt = 0; dt < 4; dt++)
                vf[kb][dt] = *(const half4*)&smem[vo + (dt * 16 + l15) * LDV + kb * 16 + quad * 4];

        #pragma unroll
        for (int qt = 0; qt < 2; qt++) {
            // S^T[key][q] in log2 domain
            floatx4 s[4];
            __builtin_amdgcn_s_setprio(1);
            #pragma unroll
            for (int nt = 0; nt < 4; nt++) {
                floatx4 cz = (floatx4){0.f, 0.f, 0.f, 0.f};
                cz = __builtin_amdgcn_mfma_f32_16x16x32_bf16(kf[nt][0], qf[qt][0], cz, 0, 0, 0);
                cz = __builtin_amdgcn_mfma_f32_16x16x32_bf16(kf[nt][1], qf[qt][1], cz, 0, 0, 0);
                s[nt] = cz;
            }
            __builtin_amdgcn_s_setprio(0);

            // static-max softmax: p = exp2(s) directly (no max tracking)
            float ps = 0.f;
            half4 pf[4];
            #pragma unroll
            for (int nt = 0; nt < 4; nt++) {
                const float p0 = __builtin_amdgcn_exp2f(s[nt][0]);
                const float p1 = __builtin_amdgcn_exp2f(s[nt][1]);
                const float p2 = __builtin_amdgcn_exp2f(s[nt][2]);
                const float p3 = __builtin_amdgcn_exp2f(s[nt][3]);
                const half2_t ha = pkrtz(p0, p1);
                const half2_t hb = pkrtz(p2, p3);
                ps = __builtin_amdgcn_fdot2(ha, one2, ps, false);
                ps = __builtin_amdgcn_fdot2(hb, one2, ps, false);
                union { half4 h4; half2_t h2[2]; } u;
                u.h2[0] = ha; u.h2[1] = hb;
                pf[nt] = u.h4;
            }
            lrun[qt] += ps;      // per-lane partial; cross-lane reduce at end

            __builtin_amdgcn_s_setprio(1);
            #pragma unroll
            for (int kb = 0; kb < 4; kb++)
                #pragma unroll
                for (int dt = 0; dt < 4; dt++)
                    acc[qt][dt] = __builtin_amdgcn_mfma_f32_16x16x16f16(vf[kb][dt], pf[kb], acc[qt][dt], 0, 0, 0);
            __builtin_amdgcn_s_setprio(0);
        }

        // ---- write prefetched V into the spare buffer ----
        #pragma unroll
        for (int i = 0; i < 8; i++)
            *(uint32_t*)&smem[von + (dc * 8 + i) * LDV + 2 * kp] = (uint32_t)ua[i] | ((uint32_t)ub[i] << 16);
    }

    // ---- deferred cross-lane reduction of the softmax denominators ----
    float l0 = lrun[0];
    l0 += __shfl_xor(l0, 16); l0 += __shfl_xor(l0, 32);
    float l1 = lrun[1];
    l1 += __shfl_xor(l1, 16); l1 += __shfl_xor(l1, 32);

    // ---- epilogue: per-wave LDS transpose, coalesced bf16 store ----
    __syncthreads();
    const float inv0 = 1.f / l0, inv1 = 1.f / l1;
    ushort_t* Tw = Tr + wid * (32 * LDV);
    #pragma unroll
    for (int qt = 0; qt < 2; qt++) {
        const float inv = qt ? inv1 : inv0;
        #pragma unroll
        for (int dt = 0; dt < 4; dt++)
            #pragma unroll
            for (int r = 0; r < 4; r++)
                Tw[(qt * 16 + l15) * LDV + dt * 16 + quad * 4 + r] = f32_to_bf16(acc[qt][dt][r] * inv);
    }
    const int row = lane >> 1, hf = lane & 1;
    const ushort_t* src = Tw + row * LDV + hf * 32;
    ushort_t* dst = ctx + ((size_t)(b * SS) + q0 + row) * DMODEL + h * HDIM + hf * 32;
    #pragma unroll
    for (int i = 0; i < 4; i++)
        *(uint4*)(dst + i * 8) = *(const uint4*)(src + i * 8);
}

extern "C" void kernel_launch(void* const* d_in, const int* in_sizes, int n_in,
                              void* d_out, int out_size, void* d_ws, size_t ws_size,
                              hipStream_t stream) {
    (void)in_sizes; (void)n_in; (void)out_size; (void)ws_size;
    const float* query = (const float*)d_in[0];
    const float* key_  = (const float*)d_in[1];
    const float* value = (const float*)d_in[2];
    const float* Wq = (const float*)d_in[3];
    const float* bq = (const float*)d_in[4];
    const float* Wk = (const float*)d_in[5];
    const float* bk = (const float*)d_in[6];
    const float* Wv = (const float*)d_in[7];
    const float* bv = (const float*)d_in[8];
    const float* Wo = (const float*)d_in[9];
    const float* bo = (const float*)d_in[10];
    float* out = (float*)d_out;

    // workspace (64 MiB = 4 x 8.4M ushorts): s0..s3
    ushort_t* s0 = (ushort_t*)d_ws;           // A_q bf16; later A_v; later Wob
    ushort_t* s1 = s0 + QKV_ELEMS;            // A_k bf16; later ctx
    ushort_t* Qw = s1 + QKV_ELEMS;            // [B,H,S,HDIM] bf16 (log2-scaled)
    ushort_t* Kw = Qw + QKV_ELEMS;            // [B,H,S,HDIM] bf16
    // d_out scratch (dead until final GEMM): weights + Vw
    ushort_t* Wqb = (ushort_t*)d_out;
    ushort_t* Wkb = Wqb + 1048576;
    ushort_t* Wvb = Wkb + 1048576;
    ushort_t* Vw  = Wvb + 1048576;            // [B,H,S,HDIM] f16

    dim3 blk(256);

    hipLaunchKernelGGL(convert_w3, dim3(512, 3), blk, 0, stream, Wq, Wk, Wv, Wqb, Wkb, Wvb);

    // Q scale = (1/sqrt(64)) * log2(e): scores exit QK^T in log2 domain
    hipLaunchKernelGGL(convert_bf16, dim3(4096), blk, 0, stream, query, s0);
    hipLaunchKernelGGL(convert_bf16, dim3(4096), blk, 0, stream, key_, s1);
    hipLaunchKernelGGL(gemm_qk, dim3(1024), blk, 0, stream,
                       s0, s1, Wqb, Wkb, bq, bk, Qw, Kw, 0.18033688011f);

    hipLaunchKernelGGL(convert_bf16, dim3(4096), blk, 0, stream, value, s0);
    hipLaunchKernelGGL((gemm_bf16<1>), dim3(512), blk, 0, stream, s0, Wvb, bv, (void*)Vw, 1.0f);

    hipLaunchKernelGGL(attn_kernel, dim3(1024), blk, 0, stream, Qw, Kw, Vw, s1);

    hipLaunchKernelGGL(convert_bf16, dim3(512), blk, 0, stream, Wo, s0);
    hipLaunchKernelGGL((gemm_bf16<2>), dim3(512), blk, 0, stream, s1, s0, bo, (void*)out, 1.0f);
}

// Round 8
// 356.790 us; speedup vs baseline: 1.6095x; 1.6095x over previous
//
#include <hip/hip_runtime.h>
#include <stdint.h>

#define DMODEL 1024
#define NHEADS 16
#define HDIM   64
#define BB     4
#define SS     2048
#define MM     (BB*SS)                      // 8192 rows
#define QKV_ELEMS ((size_t)8388608)         // B*S*DMODEL

typedef unsigned short ushort_t;
typedef __bf16    bf16x8  __attribute__((ext_vector_type(8)));
typedef _Float16  half4   __attribute__((ext_vector_type(4)));
typedef _Float16  half2_t __attribute__((ext_vector_type(2)));
typedef float     floatx4 __attribute__((ext_vector_type(4)));

__device__ inline ushort_t f32_to_bf16(float f) {
    union { float f; uint32_t u; } v; v.f = f;
    uint32_t r = v.u + 0x7FFF + ((v.u >> 16) & 1);   // RNE
    return (ushort_t)(r >> 16);
}
__device__ inline ushort_t f32_to_f16u(float f) {
    union { _Float16 h; ushort_t u; } v; v.h = (_Float16)f; return v.u;
}
__device__ inline half2_t pkrtz(float a, float b) {
    return __builtin_bit_cast(half2_t, __builtin_amdgcn_cvt_pkrtz(a, b));
}
__device__ inline void glds16(const void* g, void* l) {
    __builtin_amdgcn_global_load_lds(
        (const __attribute__((address_space(1))) unsigned int*)g,
        (__attribute__((address_space(3))) unsigned int*)l, 16, 0, 0);
}

// ---------------------------------------------------------------------------
// fp32 -> bf16 elementwise convert; each block converts 2048 elements.
// ---------------------------------------------------------------------------
__global__ __launch_bounds__(256) void convert_bf16(const float* __restrict__ in,
                                                    ushort_t* __restrict__ out) {
    size_t i = ((size_t)blockIdx.x * 256 + threadIdx.x) * 8;
    float4 a = *(const float4*)&in[i];
    float4 b = *(const float4*)&in[i + 4];
    ushort_t t[8];
    t[0] = f32_to_bf16(a.x); t[1] = f32_to_bf16(a.y);
    t[2] = f32_to_bf16(a.z); t[3] = f32_to_bf16(a.w);
    t[4] = f32_to_bf16(b.x); t[5] = f32_to_bf16(b.y);
    t[6] = f32_to_bf16(b.z); t[7] = f32_to_bf16(b.w);
    *(uint4*)&out[i] = *(uint4*)t;
}

__global__ __launch_bounds__(256) void convert_w3(
    const float* __restrict__ w0, const float* __restrict__ w1, const float* __restrict__ w2,
    ushort_t* __restrict__ o0, ushort_t* __restrict__ o1, ushort_t* __restrict__ o2) {
    const float* src = (blockIdx.y == 0) ? w0 : (blockIdx.y == 1) ? w1 : w2;
    ushort_t*    dst = (blockIdx.y == 0) ? o0 : (blockIdx.y == 1) ? o1 : o2;
    size_t i = ((size_t)blockIdx.x * 256 + threadIdx.x) * 8;
    float4 a = *(const float4*)&src[i];
    float4 b = *(const float4*)&src[i + 4];
    ushort_t t[8];
    t[0] = f32_to_bf16(a.x); t[1] = f32_to_bf16(a.y);
    t[2] = f32_to_bf16(a.z); t[3] = f32_to_bf16(a.w);
    t[4] = f32_to_bf16(b.x); t[5] = f32_to_bf16(b.y);
    t[6] = f32_to_bf16(b.z); t[7] = f32_to_bf16(b.w);
    *(uint4*)&dst[i] = *(uint4*)t;
}

// ---------------------------------------------------------------------------
// bf16 GEMM (v5 structure): 3-buffer LDS, counted vmcnt(4) pipeline,
// m-panel->XCD affinity, T2 swizzle (linear glds dest + swizzled src/read).
// OUT: 0 = bf16 scatter to [B,H,S,HDIM]; 1 = f16 scatter; 2 = fp32 [M,DMODEL]
// ---------------------------------------------------------------------------
template<int OUT>
__global__ __launch_bounds__(256) void gemm_bf16(
    const ushort_t* __restrict__ A, const ushort_t* __restrict__ W,
    const float* __restrict__ bias, void* __restrict__ O, float scale)
{
    __shared__ ushort_t As[3 * 4096];   // 3 bufs x 8 KiB
    __shared__ ushort_t Bs[3 * 4096];

    const int tid  = threadIdx.x;
    const int lane = tid & 63;
    const int quad = lane >> 4;
    const int l15  = lane & 15;
    const int wid  = tid >> 6;
    const int wr   = wid >> 1, wc = wid & 1;

    const int bid = blockIdx.x;
    const int n0  = ((bid >> 3) & 7) * 128;
    const int m0  = ((bid & 7) + ((bid >> 6) << 3)) * 128;

    floatx4 acc[4][4];
    #pragma unroll
    for (int i = 0; i < 4; i++)
        #pragma unroll
        for (int j = 0; j < 4; j++)
            acc[i][j] = (floatx4){0.f, 0.f, 0.f, 0.f};

    auto stage = [&](int kk, int bufB) {
        #pragma unroll
        for (int j = 0; j < 2; j++) {
            const int p  = tid + j * 256;
            const int ph = p << 4;
            const int lg = ph ^ (((ph >> 7) & 7) << 4);
            const int row = lg >> 6, cc = (lg >> 4) & 3;
            glds16(&A[(size_t)(m0 + row) * DMODEL + kk + cc * 8], (char*)As + bufB + ph);
            glds16(&W[(size_t)(n0 + row) * DMODEL + kk + cc * 8], (char*)Bs + bufB + ph);
        }
    };

    stage(0, 0);
    stage(32, 8192);

    int cbB = 0;
    for (int k0 = 0; k0 < DMODEL; k0 += 32) {
        if (k0 + 32 < DMODEL) asm volatile("s_waitcnt vmcnt(4)" ::: "memory");
        else                  asm volatile("s_waitcnt vmcnt(0)" ::: "memory");
        __builtin_amdgcn_s_barrier();
        __builtin_amdgcn_sched_barrier(0);
        const int k2 = k0 + 64;
        if (k2 < DMODEL) {
            int nbB = cbB + 16384; if (nbB >= 24576) nbB -= 24576;
            stage(k2, nbB);
        }
        bf16x8 af[4], bfv[4];
        #pragma unroll
        for (int i = 0; i < 4; i++) {
            const int r = wr * 64 + i * 16 + l15;
            const int L = (r << 6) | (quad << 4);
            af[i] = *(const bf16x8*)((const char*)As + cbB + (L ^ (((r >> 1) & 7) << 4)));
        }
        #pragma unroll
        for (int j = 0; j < 4; j++) {
            const int r = wc * 64 + j * 16 + l15;
            const int L = (r << 6) | (quad << 4);
            bfv[j] = *(const bf16x8*)((const char*)Bs + cbB + (L ^ (((r >> 1) & 7) << 4)));
        }
        #pragma unroll
        for (int i = 0; i < 4; i++)
            #pragma unroll
            for (int j = 0; j < 4; j++)
                acc[i][j] = __builtin_amdgcn_mfma_f32_16x16x32_bf16(af[i], bfv[j], acc[i][j], 0, 0, 0);
        cbB += 8192; if (cbB == 24576) cbB = 0;
    }

    #pragma unroll
    for (int j = 0; j < 4; j++) {
        const int n = n0 + wc * 64 + j * 16 + l15;
        const float bn = bias[n];
        #pragma unroll
        for (int i = 0; i < 4; i++) {
            #pragma unroll
            for (int r = 0; r < 4; r++) {
                const int m = m0 + wr * 64 + i * 16 + quad * 4 + r;
                float v = (acc[i][j][r] + bn) * scale;
                if (OUT == 0) {
                    const int b = m >> 11, s = m & 2047;
                    const int hh = n >> 6, dh = n & 63;
                    ((ushort_t*)O)[(((size_t)(b * NHEADS + hh)) * SS + s) * HDIM + dh] = f32_to_bf16(v);
                } else if (OUT == 1) {
                    const int b = m >> 11, s = m & 2047;
                    const int hh = n >> 6, dh = n & 63;
                    ((ushort_t*)O)[(((size_t)(b * NHEADS + hh)) * SS + s) * HDIM + dh] = f32_to_f16u(v);
                } else {
                    ((float*)O)[(size_t)m * DMODEL + n] = v;
                }
            }
        }
    }
}

// ---------------------------------------------------------------------------
// Batched Q+K projection GEMM (kept from round 7: saved ~14 us): grid 1024 =
// 2 GEMMs x 512 blocks; g = bid>>9 selects A/W/bias/out/scale. glds16 path.
// ---------------------------------------------------------------------------
__global__ __launch_bounds__(256) void gemm_qk(
    const ushort_t* __restrict__ A0, const ushort_t* __restrict__ A1,
    const ushort_t* __restrict__ W0, const ushort_t* __restrict__ W1,
    const float* __restrict__ b0, const float* __restrict__ b1,
    ushort_t* __restrict__ O0, ushort_t* __restrict__ O1, float scale0)
{
    __shared__ ushort_t As[3 * 4096];
    __shared__ ushort_t Bs[3 * 4096];

    const int tid  = threadIdx.x;
    const int lane = tid & 63;
    const int quad = lane >> 4;
    const int l15  = lane & 15;
    const int wid  = tid >> 6;
    const int wr   = wid >> 1, wc = wid & 1;

    const int bid = blockIdx.x;
    const int g   = bid >> 9;
    const int b9  = bid & 511;
    const int n0  = ((b9 >> 3) & 7) * 128;
    const int m0  = ((b9 & 7) + ((b9 >> 6) << 3)) * 128;

    const ushort_t* A    = g ? A1 : A0;
    const ushort_t* W    = g ? W1 : W0;
    const float*    bias = g ? b1 : b0;
    ushort_t*       Oz   = g ? O1 : O0;
    const float     scale = g ? 1.0f : scale0;

    floatx4 acc[4][4];
    #pragma unroll
    for (int i = 0; i < 4; i++)
        #pragma unroll
        for (int j = 0; j < 4; j++)
            acc[i][j] = (floatx4){0.f, 0.f, 0.f, 0.f};

    auto stage = [&](int kk, int bufB) {
        #pragma unroll
        for (int j = 0; j < 2; j++) {
            const int p  = tid + j * 256;
            const int ph = p << 4;
            const int lg = ph ^ (((ph >> 7) & 7) << 4);
            const int row = lg >> 6, cc = (lg >> 4) & 3;
            glds16(&A[(size_t)(m0 + row) * DMODEL + kk + cc * 8], (char*)As + bufB + ph);
            glds16(&W[(size_t)(n0 + row) * DMODEL + kk + cc * 8], (char*)Bs + bufB + ph);
        }
    };

    stage(0, 0);
    stage(32, 8192);

    int cbB = 0;
    for (int k0 = 0; k0 < DMODEL; k0 += 32) {
        if (k0 + 32 < DMODEL) asm volatile("s_waitcnt vmcnt(4)" ::: "memory");
        else                  asm volatile("s_waitcnt vmcnt(0)" ::: "memory");
        __builtin_amdgcn_s_barrier();
        __builtin_amdgcn_sched_barrier(0);
        const int k2 = k0 + 64;
        if (k2 < DMODEL) {
            int nbB = cbB + 16384; if (nbB >= 24576) nbB -= 24576;
            stage(k2, nbB);
        }
        bf16x8 af[4], bfv[4];
        #pragma unroll
        for (int i = 0; i < 4; i++) {
            const int r = wr * 64 + i * 16 + l15;
            const int L = (r << 6) | (quad << 4);
            af[i] = *(const bf16x8*)((const char*)As + cbB + (L ^ (((r >> 1) & 7) << 4)));
        }
        #pragma unroll
        for (int j = 0; j < 4; j++) {
            const int r = wc * 64 + j * 16 + l15;
            const int L = (r << 6) | (quad << 4);
            bfv[j] = *(const bf16x8*)((const char*)Bs + cbB + (L ^ (((r >> 1) & 7) << 4)));
        }
        #pragma unroll
        for (int i = 0; i < 4; i++)
            #pragma unroll
            for (int j = 0; j < 4; j++)
                acc[i][j] = __builtin_amdgcn_mfma_f32_16x16x32_bf16(af[i], bfv[j], acc[i][j], 0, 0, 0);
        cbB += 8192; if (cbB == 24576) cbB = 0;
    }

    #pragma unroll
    for (int j = 0; j < 4; j++) {
        const int n = n0 + wc * 64 + j * 16 + l15;
        const float bn = bias[n];
        #pragma unroll
        for (int i = 0; i < 4; i++) {
            #pragma unroll
            for (int r = 0; r < 4; r++) {
                const int m = m0 + wr * 64 + i * 16 + quad * 4 + r;
                const float v = (acc[i][j][r] + bn) * scale;
                const int bb = m >> 11, s = m & 2047;
                const int hh = n >> 6, dh = n & 63;
                Oz[(((size_t)(bb * NHEADS + hh)) * SS + s) * HDIM + dh] = f32_to_bf16(v);
            }
        }
    }
}

// ---------------------------------------------------------------------------
// Flash attention v3 (EXACT round-5 form, 98.8 us, VGPR=64). Static-max
// softmax (log2-domain scores, p = exp2(s), no running max); PV 16x16x16 f16.
// DO NOT add control flow around the acc update (round-1 spill) and DO NOT
// add s_setprio (round-7 spill: FETCH 784 MB / WRITE 459 MB scratch traffic
// -- this kernel sits exactly at the 64-VGPR occupancy step; any scheduling
// pin tips it into scratch).
// ---------------------------------------------------------------------------
__global__ __launch_bounds__(256, 4) void attn_kernel(
    const ushort_t* __restrict__ Q, const ushort_t* __restrict__ K,
    const ushort_t* __restrict__ V, ushort_t* __restrict__ ctx)
{
    constexpr int LDV = 72;
    constexpr int VOFF = 2 * 4096;                       // Vt region base
    __shared__ ushort_t smem[2 * 4096 + 2 * 64 * LDV];   // 34.0 KiB
    ushort_t* Tr = smem;                                 // epilogue scratch

    const int tid  = threadIdx.x;
    const int lane = tid & 63;
    const int wid  = tid >> 6;
    const int quad = lane >> 4;
    const int l15  = lane & 15;
    const int bid  = blockIdx.x;
    const int bh   = (bid & 7) * 8 + (bid >> 7);          // same head -> same XCD
    const int b    = bh >> 4, h = bh & 15;
    const int q0   = ((bid >> 3) & 15) * 128 + wid * 32;

    const ushort_t* Qb = Q + (size_t)bh * SS * HDIM;
    const ushort_t* Kb = K + (size_t)bh * SS * HDIM;
    const ushort_t* Vb = V + (size_t)bh * SS * HDIM;

    // Q fragments (B-operand: lane&15 = q, quad*8+j = dim), 2 q-tiles
    bf16x8 qf[2][2];
    #pragma unroll
    for (int qt = 0; qt < 2; qt++)
        #pragma unroll
        for (int c = 0; c < 2; c++)
            qf[qt][c] = *(const bf16x8*)&Qb[(size_t)(q0 + qt * 16 + l15) * HDIM + c * 32 + quad * 8];

    floatx4 acc[2][4];
    #pragma unroll
    for (int qt = 0; qt < 2; qt++)
        #pragma unroll
        for (int dt = 0; dt < 4; dt++)
            acc[qt][dt] = (floatx4){0.f, 0.f, 0.f, 0.f};
    float lrun[2] = {0.f, 0.f};     // per-lane partial sum of p (reduced at end)

    const int kp = tid & 31;    // key pair for V staging
    const int dc = tid >> 5;    // dim chunk for V staging

    // ---- prologue: stage tile 0 ----
    #pragma unroll
    for (int j = 0; j < 2; j++) {
        const int p = tid + j * 256, row = p >> 3, cc = (p & 7) ^ (row & 7);
        glds16(&Kb[(size_t)row * HDIM + cc * 8], &smem[p * 8]);
    }
    {
        ushort_t ua[8], ub[8];
        *(uint4*)ua = *(const uint4*)&Vb[(size_t)(2 * kp) * HDIM + dc * 8];
        *(uint4*)ub = *(const uint4*)&Vb[(size_t)(2 * kp + 1) * HDIM + dc * 8];
        #pragma unroll
        for (int i = 0; i < 8; i++)
            *(uint32_t*)&smem[VOFF + (dc * 8 + i) * LDV + 2 * kp] = (uint32_t)ua[i] | ((uint32_t)ub[i] << 16);
    }

    const half2_t one2 = {(_Float16)1.f, (_Float16)1.f};

    for (int kt = 0; kt < SS; kt += 64) {
        const int cur = ((kt >> 6) & 1);
        const int ko  = cur * 4096;                  // current K buf offset
        const int kon = 4096 - ko;                   // next K buf offset
        const int vo  = VOFF + cur * (64 * LDV);     // current Vt buf offset
        const int von = VOFF + (64 * LDV) - cur * (64 * LDV);
        __syncthreads();   // tile(kt) staged; other buffers free

        // ---- prefetch tile kt+64 (wraps on last iter; harmless) ----
        const int ktn = (kt + 64) & (SS - 1);
        #pragma unroll
        for (int j = 0; j < 2; j++) {
            const int p = tid + j * 256, row = p >> 3, cc = (p & 7) ^ (row & 7);
            glds16(&Kb[(size_t)(ktn + row) * HDIM + cc * 8], &smem[kon + p * 8]);
        }
        ushort_t ua[8], ub[8];
        *(uint4*)ua = *(const uint4*)&Vb[(size_t)(ktn + 2 * kp) * HDIM + dc * 8];
        *(uint4*)ub = *(const uint4*)&Vb[(size_t)(ktn + 2 * kp + 1) * HDIM + dc * 8];

        // ---- fragments for tile kt ----
        bf16x8 kf[4][2];
        #pragma unroll
        for (int nt = 0; nt < 4; nt++) {
            const int row = nt * 16 + l15;
            #pragma unroll
            for (int c = 0; c < 2; c++) {
                const int pos = (c * 4 + quad) ^ (row & 7);
                kf[nt][c] = *(const bf16x8*)&smem[ko + row * 64 + pos * 8];
            }
        }
        half4 vf[4][4];
        #pragma unroll
        for (int kb = 0; kb < 4; kb++)
            #pragma unroll
            for (int dt = 0; dt < 4; dt++)
                vf[kb][dt] = *(const half4*)&smem[vo + (dt * 16 + l15) * LDV + kb * 16 + quad * 4];

        #pragma unroll
        for (int qt = 0; qt < 2; qt++) {
            // S^T[key][q] in log2 domain
            floatx4 s[4];
            #pragma unroll
            for (int nt = 0; nt < 4; nt++) {
                floatx4 cz = (floatx4){0.f, 0.f, 0.f, 0.f};
                cz = __builtin_amdgcn_mfma_f32_16x16x32_bf16(kf[nt][0], qf[qt][0], cz, 0, 0, 0);
                cz = __builtin_amdgcn_mfma_f32_16x16x32_bf16(kf[nt][1], qf[qt][1], cz, 0, 0, 0);
                s[nt] = cz;
            }

            // static-max softmax: p = exp2(s) directly (no max tracking)
            float ps = 0.f;
            half4 pf[4];
            #pragma unroll
            for (int nt = 0; nt < 4; nt++) {
                const float p0 = __builtin_amdgcn_exp2f(s[nt][0]);
                const float p1 = __builtin_amdgcn_exp2f(s[nt][1]);
                const float p2 = __builtin_amdgcn_exp2f(s[nt][2]);
                const float p3 = __builtin_amdgcn_exp2f(s[nt][3]);
                const half2_t ha = pkrtz(p0, p1);
                const half2_t hb = pkrtz(p2, p3);
                ps = __builtin_amdgcn_fdot2(ha, one2, ps, false);
                ps = __builtin_amdgcn_fdot2(hb, one2, ps, false);
                union { half4 h4; half2_t h2[2]; } u;
                u.h2[0] = ha; u.h2[1] = hb;
                pf[nt] = u.h4;
            }
            lrun[qt] += ps;      // per-lane partial; cross-lane reduce at end

            #pragma unroll
            for (int kb = 0; kb < 4; kb++)
                #pragma unroll
                for (int dt = 0; dt < 4; dt++)
                    acc[qt][dt] = __builtin_amdgcn_mfma_f32_16x16x16f16(vf[kb][dt], pf[kb], acc[qt][dt], 0, 0, 0);
        }

        // ---- write prefetched V into the spare buffer ----
        #pragma unroll
        for (int i = 0; i < 8; i++)
            *(uint32_t*)&smem[von + (dc * 8 + i) * LDV + 2 * kp] = (uint32_t)ua[i] | ((uint32_t)ub[i] << 16);
    }

    // ---- deferred cross-lane reduction of the softmax denominators ----
    float l0 = lrun[0];
    l0 += __shfl_xor(l0, 16); l0 += __shfl_xor(l0, 32);
    float l1 = lrun[1];
    l1 += __shfl_xor(l1, 16); l1 += __shfl_xor(l1, 32);

    // ---- epilogue: per-wave LDS transpose, coalesced bf16 store ----
    __syncthreads();
    const float inv0 = 1.f / l0, inv1 = 1.f / l1;
    ushort_t* Tw = Tr + wid * (32 * LDV);
    #pragma unroll
    for (int qt = 0; qt < 2; qt++) {
        const float inv = qt ? inv1 : inv0;
        #pragma unroll
        for (int dt = 0; dt < 4; dt++)
            #pragma unroll
            for (int r = 0; r < 4; r++)
                Tw[(qt * 16 + l15) * LDV + dt * 16 + quad * 4 + r] = f32_to_bf16(acc[qt][dt][r] * inv);
    }
    const int row = lane >> 1, hf = lane & 1;
    const ushort_t* src = Tw + row * LDV + hf * 32;
    ushort_t* dst = ctx + ((size_t)(b * SS) + q0 + row) * DMODEL + h * HDIM + hf * 32;
    #pragma unroll
    for (int i = 0; i < 4; i++)
        *(uint4*)(dst + i * 8) = *(const uint4*)(src + i * 8);
}

extern "C" void kernel_launch(void* const* d_in, const int* in_sizes, int n_in,
                              void* d_out, int out_size, void* d_ws, size_t ws_size,
                              hipStream_t stream) {
    (void)in_sizes; (void)n_in; (void)out_size; (void)ws_size;
    const float* query = (const float*)d_in[0];
    const float* key_  = (const float*)d_in[1];
    const float* value = (const float*)d_in[2];
    const float* Wq = (const float*)d_in[3];
    const float* bq = (const float*)d_in[4];
    const float* Wk = (const float*)d_in[5];
    const float* bk = (const float*)d_in[6];
    const float* Wv = (const float*)d_in[7];
    const float* bv = (const float*)d_in[8];
    const float* Wo = (const float*)d_in[9];
    const float* bo = (const float*)d_in[10];
    float* out = (float*)d_out;

    // workspace (64 MiB = 4 x 8.4M ushorts): s0..s3
    ushort_t* s0 = (ushort_t*)d_ws;           // A_q bf16; later A_v; later Wob
    ushort_t* s1 = s0 + QKV_ELEMS;            // A_k bf16; later ctx
    ushort_t* Qw = s1 + QKV_ELEMS;            // [B,H,S,HDIM] bf16 (log2-scaled)
    ushort_t* Kw = Qw + QKV_ELEMS;            // [B,H,S,HDIM] bf16
    // d_out scratch (dead until final GEMM): weights + Vw
    ushort_t* Wqb = (ushort_t*)d_out;
    ushort_t* Wkb = Wqb + 1048576;
    ushort_t* Wvb = Wkb + 1048576;
    ushort_t* Vw  = Wvb + 1048576;            // [B,H,S,HDIM] f16

    dim3 blk(256);

    hipLaunchKernelGGL(convert_w3, dim3(512, 3), blk, 0, stream, Wq, Wk, Wv, Wqb, Wkb, Wvb);

    // Q scale = (1/sqrt(64)) * log2(e): scores exit QK^T in log2 domain
    hipLaunchKernelGGL(convert_bf16, dim3(4096), blk, 0, stream, query, s0);
    hipLaunchKernelGGL(convert_bf16, dim3(4096), blk, 0, stream, key_, s1);
    hipLaunchKernelGGL(gemm_qk, dim3(1024), blk, 0, stream,
                       s0, s1, Wqb, Wkb, bq, bk, Qw, Kw, 0.18033688011f);

    hipLaunchKernelGGL(convert_bf16, dim3(4096), blk, 0, stream, value, s0);
    hipLaunchKernelGGL((gemm_bf16<1>), dim3(512), blk, 0, stream, s0, Wvb, bv, (void*)Vw, 1.0f);

    hipLaunchKernelGGL(attn_kernel, dim3(1024), blk, 0, stream, Qw, Kw, Vw, s1);

    hipLaunchKernelGGL(convert_bf16, dim3(512), blk, 0, stream, Wo, s0);
    hipLaunchKernelGGL((gemm_bf16<2>), dim3(512), blk, 0, stream, s1, s0, bo, (void*)out, 1.0f);
}